// Round 6
// baseline (2533.928 us; speedup 1.0000x reference)
//
#include <hip/hip_runtime.h>
#include <stdint.h>

// ---------------------------------------------------------------------------
// ConditionalDecoder: emb-gather -> LSTM x2 -> FiLM -> vocab GEMM
// B=16, T=256, V=32000, E=H=Z=256, 4H=1024
// Round 6: fully register-resident W_hh in the per-sample LSTM.
//   Key fact: 512 regs/wave (256 VGPR + 256 AGPR unified) x 2 waves/SIMD
//   fits the 2048-reg/SIMD file; MFMA B-operands read AGPRs directly.
//   All 64 B-frags (256 regs) live in registers for all 256 steps ->
//   zero per-step W traffic (r5 was LDS-pipe-bound streaming 144KB/step).
//   LDS now holds only the 0.5KB h double-buffer.
// ---------------------------------------------------------------------------

#define B_  16
#define T_  256
#define H_  256
#define V_  32000
#define G4  1024

#define LWAVES 8
#define LTPB   512

typedef unsigned short u16;
typedef __attribute__((ext_vector_type(8))) short  short8;
typedef __attribute__((ext_vector_type(4))) short  short4v;
typedef __attribute__((ext_vector_type(4))) float  f32x4;

static __device__ __forceinline__ float bf2f(u16 u) {
  uint32_t i = ((uint32_t)u) << 16;
  return __builtin_bit_cast(float, i);
}
static __device__ __forceinline__ u16 f2bf(float f) {
  uint32_t i = __builtin_bit_cast(uint32_t, f);
  uint32_t lsb = (i >> 16) & 1u;
  i += 0x7fffu + lsb;
  return (u16)(i >> 16);
}
static __device__ __forceinline__ float sigf(float x) {
  return 1.0f / (1.0f + __expf(-x));
}
static __device__ __forceinline__ float tanhfast(float x) {
  return 1.0f - 2.0f / (1.0f + __expf(2.0f * x));
}

// ------------------------------ prep kernels -------------------------------

__global__ void k_convert(const float* __restrict__ src, u16* __restrict__ dst, int n) {
  int i = blockIdx.x * blockDim.x + threadIdx.x;
  int stride = gridDim.x * blockDim.x;
  for (; i < n; i += stride) dst[i] = f2bf(src[i]);
}

__global__ void k_addbias(const float* __restrict__ a, const float* __restrict__ b,
                          float* __restrict__ dst, int n) {
  int i = blockIdx.x * blockDim.x + threadIdx.x;
  if (i < n) dst[i] = a[i] + b[i];
}

// Pack W_hh (1024x256 f32) into MFMA-frag order, bf16:
// pk[(((w*64 + f)*64) + lane)*8 + j], f = tile*8 + ks,
// row = (tile>>1)*256 + w*32 + (tile&1)*16 + (lane&15), col = ks*32 + (lane>>4)*8 + j
__global__ void k_packW(const float* __restrict__ Whh, u16* __restrict__ pk) {
  int i = blockIdx.x * blockDim.x + threadIdx.x;   // 32768
  int lane = i & 63;
  int f    = (i >> 6) & 63;
  int w    = i >> 12;
  int tile = f >> 3, ks = f & 7;
  int row = (tile >> 1) * 256 + w * 32 + (tile & 1) * 16 + (lane & 15);
  int col = ks * 32 + (lane >> 4) * 8;
  const float* src = Whh + (size_t)row * 256 + col;
  short8 v;
  #pragma unroll
  for (int j = 0; j < 8; j++) v[j] = (short)f2bf(src[j]);
  *(short8*)(pk + (size_t)i * 8) = v;
}

// gamma = z@Wg.T + bg ; beta = z@Wb.T + bb   (each (16,256))
__global__ void k_film(const float* __restrict__ z,
                       const float* __restrict__ Wg, const float* __restrict__ bg,
                       const float* __restrict__ Wb, const float* __restrict__ bb,
                       float* __restrict__ gamma, float* __restrict__ beta) {
  int tid = blockIdx.x * blockDim.x + threadIdx.x;   // 8192
  int which = tid >> 12;
  int o = tid & 4095;
  int b = o >> 8, h = o & 255;
  const float* W  = which ? Wb : Wg;
  const float* bi = which ? bb : bg;
  float acc = bi[h];
  const float* zr = z + b * 256;
  const float* wr = W + h * 256;
  #pragma unroll 8
  for (int k = 0; k < 256; k++) acc += zr[k] * wr[k];
  (which ? beta : gamma)[o] = acc;
}

// x[b][t][:] = (seq[b][t]==0 ? 0 : emb[seq[b][t]])  as bf16
__global__ void k_gather(const int* __restrict__ seq, const float* __restrict__ emb,
                         u16* __restrict__ xb) {
  int i = blockIdx.x * blockDim.x + threadIdx.x;     // B*T*(E/4) = 262144
  int n = B_ * T_ * (H_ / 4);
  if (i >= n) return;
  int e4 = i & 63;
  int bt = i >> 6;
  int t = bt & 255, b = bt >> 8;
  int row = seq[b * 257 + t];
  short4v p;
  if (row == 0) {
    p[0] = 0; p[1] = 0; p[2] = 0; p[3] = 0;
  } else {
    const f32x4 v = *(const f32x4*)(emb + (size_t)row * 256 + e4 * 4);
    p[0] = (short)f2bf(v[0]); p[1] = (short)f2bf(v[1]);
    p[2] = (short)f2bf(v[2]); p[3] = (short)f2bf(v[3]);
  }
  *(short4v*)(xb + (size_t)bt * 256 + e4 * 4) = p;
}

// ------------------------------ bf16 GEMM ----------------------------------
// C(M,N) fp32 = A(M,K)bf16 @ B(N,K)bf16^T + bias(N). M,N mult of 128, K mult of 32.
// permX: permute output column so the LSTM consumer's 8 gate values per
// (w,l15) are contiguous: pos = w*128 + l15*8 + g*2 + cb  (N must be 1024).

__global__ __launch_bounds__(256) void k_gemm_bt(
    const u16* __restrict__ A, const u16* __restrict__ Bm,
    const float* __restrict__ bias, float* __restrict__ C,
    int M, int N, int K, int permX) {
  __shared__ u16 sA[128 * 40];
  __shared__ u16 sB[128 * 40];
  const int tid  = threadIdx.x;
  const int lane = tid & 63;
  const int wv   = tid >> 6;
  const int wr   = wv >> 1, wc = wv & 1;
  const int m0 = blockIdx.y * 128, n0 = blockIdx.x * 128;
  const int rr = tid >> 2;
  const int cc = (tid & 3) * 8;

  f32x4 acc[4][4];
  #pragma unroll
  for (int m = 0; m < 4; m++)
    #pragma unroll
    for (int n = 0; n < 4; n++) acc[m][n] = (f32x4){0.f, 0.f, 0.f, 0.f};

  for (int ks = 0; ks < K; ks += 32) {
    short8 va0 = *(const short8*)(A  + (size_t)(m0 + rr)      * K + ks + cc);
    short8 va1 = *(const short8*)(A  + (size_t)(m0 + rr + 64) * K + ks + cc);
    short8 vb0 = *(const short8*)(Bm + (size_t)(n0 + rr)      * K + ks + cc);
    short8 vb1 = *(const short8*)(Bm + (size_t)(n0 + rr + 64) * K + ks + cc);
    __syncthreads();
    *(short8*)&sA[(rr)      * 40 + cc] = va0;
    *(short8*)&sA[(rr + 64) * 40 + cc] = va1;
    *(short8*)&sB[(rr)      * 40 + cc] = vb0;
    *(short8*)&sB[(rr + 64) * 40 + cc] = vb1;
    __syncthreads();
    const int kc = (lane >> 4) * 8;
    short8 af[4], bfr[4];
    #pragma unroll
    for (int m = 0; m < 4; m++)
      af[m] = *(const short8*)&sA[(wr * 64 + m * 16 + (lane & 15)) * 40 + kc];
    #pragma unroll
    for (int n = 0; n < 4; n++)
      bfr[n] = *(const short8*)&sB[(wc * 64 + n * 16 + (lane & 15)) * 40 + kc];
    #pragma unroll
    for (int m = 0; m < 4; m++)
      #pragma unroll
      for (int n = 0; n < 4; n++)
        acc[m][n] = __builtin_amdgcn_mfma_f32_16x16x32_bf16(af[m], bfr[n], acc[m][n], 0, 0, 0);
  }

  #pragma unroll
  for (int m = 0; m < 4; m++) {
    int row = m0 + wr * 64 + m * 16 + ((lane >> 4) << 2);
    #pragma unroll
    for (int n = 0; n < 4; n++) {
      int col = n0 + wc * 64 + n * 16 + (lane & 15);
      float bv = bias[col];
      int ocol = col;
      if (permX) {
        int g = col >> 8, r = col & 255;
        ocol = (r >> 5) * 128 + (col & 15) * 8 + g * 2 + ((r >> 4) & 1);
      }
      #pragma unroll
      for (int i = 0; i < 4; i++)
        C[(size_t)(row + i) * N + ocol] = acc[m][n][i] + bv;
    }
  }
}

// ------------------------- per-sample LSTM ---------------------------------
// Block = one sample. 8 waves; wave w owns h-cols [w*32,w*32+16) (cb=0) and
// [w*32+16,w*32+32) (cb=1) for all 4 gates = 8 MFMA N-tiles (tile = gate*2+cb).
// ALL 64 B-frags resident in registers (VGPR+AGPR; 256 regs) for all steps.
// A = h(t-1) bf16 replicated over 16 MFMA rows (only row data in lanes'
// l15-chunks matters; replication is free). Raw s_barrier per step (LDS-only
// handoff, no vmcnt drain). X permuted fp32: thread's 8 gate values at
// (s*T+t)*1024 + (w*16+l15)*8, order {i0,i1,f0,f1, g0,g1,o0,o1}.

__global__ __launch_bounds__(LTPB, 2) void k_lstm_sample(
    const float* __restrict__ Xpre,    // (B*T, 1024) fp32 permuted
    const u16* __restrict__ Wpk,       // packed W_hh frags (see k_packW)
    u16* __restrict__ outb,            // (B,T,H) bf16
    const float* __restrict__ gamma, const float* __restrict__ beta,
    int mode) {
  __shared__ u16 hbuf[2][288];                  // h double buffer (bf16)

  const int s    = blockIdx.x;
  const int tid  = threadIdx.x;
  const int lane = tid & 63;
  const int w    = tid >> 6;
  const int l15  = lane & 15;
  const int lhi  = lane >> 4;

  // ---- load all 64 B-frags into registers (coalesced from packed buffer) ----
  short8 wreg[64];
  {
    const u16* base = Wpk + (((size_t)w * 64) * 64 + lane) * 8;
    #pragma unroll
    for (int f = 0; f < 64; ++f)
      wreg[f] = *(const short8*)(base + (size_t)f * 64 * 8);
  }

  const int col0 = w * 32 + l15;
  const int col1 = col0 + 16;
  float cs0 = 0.f, cs1 = 0.f;
  float gm0 = 1.f, gm1 = 1.f, bt0 = 0.f, bt1 = 0.f;
  if (mode) {
    gm0 = gamma[s * 256 + col0]; bt0 = beta[s * 256 + col0];
    gm1 = gamma[s * 256 + col1]; bt1 = beta[s * 256 + col1];
  }

  const float* xptr = Xpre + (size_t)s * T_ * 1024 + (size_t)(w * 16 + l15) * 8;

  // ---- step t = 0 (no recurrent term) ----
  f32x4 xa = *(const f32x4*)(xptr);
  f32x4 xg = *(const f32x4*)(xptr + 4);
  {
    float cn0 = sigf(xa[2]) * cs0 + sigf(xa[0]) * tanhfast(xg[0]);
    float hn0 = sigf(xg[2]) * tanhfast(cn0);
    cs0 = cn0;
    float cn1 = sigf(xa[3]) * cs1 + sigf(xa[1]) * tanhfast(xg[1]);
    float hn1 = sigf(xg[3]) * tanhfast(cn1);
    cs1 = cn1;
    u16 h0 = f2bf(hn0), h1 = f2bf(hn1);
    if (lhi == 0) {
      hbuf[0][col0] = h0;
      hbuf[0][col1] = h1;
      outb[(size_t)(s * T_) * 256 + col0] = mode ? f2bf(gm0 * hn0 + bt0) : h0;
      outb[(size_t)(s * T_) * 256 + col1] = mode ? f2bf(gm1 * hn1 + bt1) : h1;
    }
  }
  asm volatile("s_waitcnt lgkmcnt(0)" ::: "memory");
  __builtin_amdgcn_sched_barrier(0);
  __builtin_amdgcn_s_barrier();
  __builtin_amdgcn_sched_barrier(0);

  // preload X for t=1
  xa = *(const f32x4*)(xptr + 1024);
  xg = *(const f32x4*)(xptr + 1024 + 4);

  for (int t = 1; t < T_; ++t) {
    // prefetch X for t+1 (clamped) -- consumed next iteration
    const float* xn = xptr + (size_t)((t + 1 < T_) ? t + 1 : t) * 1024;
    f32x4 na = *(const f32x4*)(xn);
    f32x4 ng = *(const f32x4*)(xn + 4);

    // ---- MFMA: h(t-1) @ Whh^T, all B-frags from registers ----
    const u16* hrd = hbuf[(t + 1) & 1];
    f32x4 acc[8];
    #pragma unroll
    for (int i = 0; i < 8; ++i) acc[i] = (f32x4){0.f, 0.f, 0.f, 0.f};
    #pragma unroll
    for (int ks = 0; ks < 8; ++ks) {
      short8 a = *(const short8*)&hrd[ks * 32 + lhi * 8];
      #pragma unroll
      for (int i = 0; i < 8; ++i)
        acc[i] = __builtin_amdgcn_mfma_f32_16x16x32_bf16(a, wreg[i * 8 + ks], acc[i], 0, 0, 0);
    }

    // ---- nonlinearity (rows replicated; row-0 slice in acc[i][0]) ----
    {
      float iv = acc[0][0] + xa[0], fv = acc[2][0] + xa[2];
      float gv = acc[4][0] + xg[0], ov = acc[6][0] + xg[2];
      float cn = sigf(fv) * cs0 + sigf(iv) * tanhfast(gv);
      float hn = sigf(ov) * tanhfast(cn);
      cs0 = cn;
      u16 hv = f2bf(hn);
      if (lhi == 0) {
        hbuf[t & 1][col0] = hv;
        outb[((size_t)(s * T_ + t)) * 256 + col0] =
            mode ? f2bf(gm0 * hn + bt0) : hv;
      }
    }
    {
      float iv = acc[1][0] + xa[1], fv = acc[3][0] + xa[3];
      float gv = acc[5][0] + xg[1], ov = acc[7][0] + xg[3];
      float cn = sigf(fv) * cs1 + sigf(iv) * tanhfast(gv);
      float hn = sigf(ov) * tanhfast(cn);
      cs1 = cn;
      u16 hv = f2bf(hn);
      if (lhi == 0) {
        hbuf[t & 1][col1] = hv;
        outb[((size_t)(s * T_ + t)) * 256 + col1] =
            mode ? f2bf(gm1 * hn + bt1) : hv;
      }
    }

    // ---- raw barrier: LDS drained, VMEM left in flight ----
    asm volatile("s_waitcnt lgkmcnt(0)" ::: "memory");
    __builtin_amdgcn_sched_barrier(0);
    __builtin_amdgcn_s_barrier();
    __builtin_amdgcn_sched_barrier(0);

    xa = na;
    xg = ng;
  }
}

// ------------------------------ launcher -----------------------------------

extern "C" void kernel_launch(void* const* d_in, const int* in_sizes, int n_in,
                              void* d_out, int out_size, void* d_ws, size_t ws_size,
                              hipStream_t stream) {
  const float* z    = (const float*)d_in[0];
  const int*   seq  = (const int*)  d_in[1];
  const float* emb  = (const float*)d_in[2];
  const float* Wg   = (const float*)d_in[3];
  const float* bg   = (const float*)d_in[4];
  const float* Wb   = (const float*)d_in[5];
  const float* bb   = (const float*)d_in[6];
  const float* Wih0 = (const float*)d_in[7];
  const float* Whh0 = (const float*)d_in[8];
  const float* bih0 = (const float*)d_in[9];
  const float* bhh0 = (const float*)d_in[10];
  const float* Wih1 = (const float*)d_in[11];
  const float* Whh1 = (const float*)d_in[12];
  const float* bih1 = (const float*)d_in[13];
  const float* bhh1 = (const float*)d_in[14];
  const float* Wout = (const float*)d_in[15];
  const float* bout = (const float*)d_in[16];

  char* ws = (char*)d_ws;
  size_t off = 0;
  auto take = [&](size_t bytes) -> char* {
    char* p = ws + off;
    off = (off + bytes + 255) & ~(size_t)255;
    return p;
  };
  float* gamma  = (float*)take(B_ * H_ * 4);
  float* beta   = (float*)take(B_ * H_ * 4);
  float* b01    = (float*)take(G4 * 4);
  float* b11    = (float*)take(G4 * 4);
  u16*   Wih0b  = (u16*)  take((size_t)G4 * H_ * 2);
  u16*   Wpk0   = (u16*)  take((size_t)G4 * H_ * 2);
  u16*   Wih1b  = (u16*)  take((size_t)G4 * H_ * 2);
  u16*   Wpk1   = (u16*)  take((size_t)G4 * H_ * 2);
  u16*   Woutb  = (u16*)  take((size_t)V_ * H_ * 2);
  u16*   xb     = (u16*)  take((size_t)B_ * T_ * H_ * 2);
  float* X      = (float*)take((size_t)B_ * T_ * G4 * 4);
  u16*   h1b    = (u16*)  take((size_t)B_ * T_ * H_ * 2);
  u16*   filmb  = (u16*)  take((size_t)B_ * T_ * H_ * 2);
  (void)ws_size; (void)in_sizes; (void)n_in; (void)out_size;

  // prep
  k_convert<<<256, 256, 0, stream>>>(Wih0, Wih0b, G4 * H_);
  k_convert<<<256, 256, 0, stream>>>(Wih1, Wih1b, G4 * H_);
  k_convert<<<1024, 256, 0, stream>>>(Wout, Woutb, V_ * H_);
  k_packW<<<128, 256, 0, stream>>>(Whh0, Wpk0);
  k_packW<<<128, 256, 0, stream>>>(Whh1, Wpk1);
  k_addbias<<<4, 256, 0, stream>>>(bih0, bhh0, b01, G4);
  k_addbias<<<4, 256, 0, stream>>>(bih1, bhh1, b11, G4);
  k_film<<<32, 256, 0, stream>>>(z, Wg, bg, Wb, bb, gamma, beta);
  k_gather<<<1024, 256, 0, stream>>>(seq, emb, xb);

  // layer 0 input projection (permuted X layout)
  k_gemm_bt<<<dim3(G4 / 128, (B_ * T_) / 128), 256, 0, stream>>>(
      xb, Wih0b, b01, X, B_ * T_, G4, H_, 1);

  // layer 0 recurrence: one block per sample, no inter-block sync
  k_lstm_sample<<<B_, LTPB, 0, stream>>>(X, Wpk0, h1b, gamma, beta, 0);

  // layer 1 input projection (permuted X layout)
  k_gemm_bt<<<dim3(G4 / 128, (B_ * T_) / 128), 256, 0, stream>>>(
      h1b, Wih1b, b11, X, B_ * T_, G4, H_, 1);

  // layer 1 recurrence (FiLM fused into output)
  k_lstm_sample<<<B_, LTPB, 0, stream>>>(X, Wpk1, filmb, gamma, beta, 1);

  // logits = filmed @ Wout^T + b_out
  k_gemm_bt<<<dim3(V_ / 128, (B_ * T_) / 128), 256, 0, stream>>>(
      filmb, Woutb, bout, (float*)d_out, B_ * T_, V_, H_, 0);
}

// Round 7
// 1697.302 us; speedup vs baseline: 1.4929x; 1.4929x over previous
//
#include <hip/hip_runtime.h>
#include <stdint.h>

// ---------------------------------------------------------------------------
// ConditionalDecoder: emb-gather -> LSTM x2 -> FiLM -> vocab GEMM
// B=16, T=256, V=32000, E=H=Z=256, 4H=1024
// Round 7: FULL W_hh register residency via 4 waves x 512 regs/wave.
//   - LTPB=256, launch_bounds(256,1): 1 wave/SIMD -> 512 regs (VGPR+AGPR)
//   - per wave: 96 bf16 B-frags (gates i,f,g) + 32 fp8-e4m3 B-frags (gate o)
//   - own OCP e4m3fn encoder used for BOTH W-pack and per-step h (consistent)
//   - 2 MFMA phases (acc<=32 live): A={i,f}, B={g bf16, o fp8}
//   - X permuted so each lane's 4 gates = one f32x4, prefetched 1 step ahead
// ---------------------------------------------------------------------------

#define B_  16
#define T_  256
#define H_  256
#define V_  32000
#define G4  1024

#define LTPB 256   // 4 waves

typedef unsigned short u16;
typedef unsigned long long u64;
typedef __attribute__((ext_vector_type(8))) short  short8;
typedef __attribute__((ext_vector_type(4))) short  short4v;
typedef __attribute__((ext_vector_type(4))) float  f32x4;

static __device__ __forceinline__ float bf2f(u16 u) {
  uint32_t i = ((uint32_t)u) << 16;
  return __builtin_bit_cast(float, i);
}
static __device__ __forceinline__ u16 f2bf(float f) {
  uint32_t i = __builtin_bit_cast(uint32_t, f);
  uint32_t lsb = (i >> 16) & 1u;
  i += 0x7fffu + lsb;
  return (u16)(i >> 16);
}
static __device__ __forceinline__ float sigf(float x) {
  return 1.0f / (1.0f + __expf(-x));
}
static __device__ __forceinline__ float tanhfast(float x) {
  return 1.0f - 2.0f / (1.0f + __expf(2.0f * x));
}

// OCP e4m3fn encode (bias 7, max finite 448 = 0x7E, RNE). Used for BOTH the
// packed W bytes and the per-step h bytes -> A/B formats match by construction.
static __device__ __forceinline__ uint32_t f32_to_e4m3(float f) {
  uint32_t u = __builtin_bit_cast(uint32_t, f);
  uint32_t s = (u >> 24) & 0x80u;
  uint32_t mag = u & 0x7fffffffu;
  if (mag >= 0x43E00000u) return s | 0x7Eu;          // >=448 -> 448
  if (mag < 0x3C800000u) {                           // < 2^-6 -> subnormal
    float af = __builtin_bit_cast(float, mag);
    int q = (int)rintf(af * 512.0f);                 // value = q * 2^-9
    if (q >= 8) return s | 0x08u;
    return s | (uint32_t)q;
  }
  uint32_t lsb = (mag >> 20) & 1u;
  mag += 0x7ffffu + lsb;                             // RNE on 20 dropped bits
  int e = (int)(mag >> 23) - 120;                    // -127 + 7
  uint32_t m3 = (mag >> 20) & 7u;
  if (e >= 16) return s | 0x7Eu;
  return s | ((uint32_t)e << 3) | m3;
}

static __device__ __forceinline__ float sel4(int c, float a, float b, float d, float e) {
  float r = (c == 0) ? a : b;
  r = (c == 2) ? d : r;
  r = (c == 3) ? e : r;
  return r;
}

// ------------------------------ prep kernels -------------------------------

__global__ void k_convert(const float* __restrict__ src, u16* __restrict__ dst, int n) {
  int i = blockIdx.x * blockDim.x + threadIdx.x;
  int stride = gridDim.x * blockDim.x;
  for (; i < n; i += stride) dst[i] = f2bf(src[i]);
}

__global__ void k_addbias(const float* __restrict__ a, const float* __restrict__ b,
                          float* __restrict__ dst, int n) {
  int i = blockIdx.x * blockDim.x + threadIdx.x;
  if (i < n) dst[i] = a[i] + b[i];
}

// Pack bf16 W frags for gates i,f,g (96 frags/wave).
// idx i = ((w*96 + fb)*64 + lane); fb = (g*4+cb)*8 + ks, g in {0,1,2}
// row = g*256 + w*64 + cb*16 + (lane&15); k = ks*32 + (lane>>4)*8 + j
__global__ void k_packWb(const float* __restrict__ Whh, u16* __restrict__ pk) {
  int i = blockIdx.x * blockDim.x + threadIdx.x;   // 24576
  int lane = i & 63;
  int fb = (i >> 6) % 96;
  int w  = (i >> 6) / 96;
  int g = fb >> 5, cb = (fb >> 3) & 3, ks = fb & 7;
  int row = g * 256 + w * 64 + cb * 16 + (lane & 15);
  int kb  = ks * 32 + (lane >> 4) * 8;
  const float* src = Whh + (size_t)row * 256 + kb;
  short8 v;
  #pragma unroll
  for (int j = 0; j < 8; j++) v[j] = (short)f2bf(src[j]);
  *(short8*)(pk + (size_t)i * 8) = v;
}

// Pack fp8 W frags for gate o (32 frags/wave).
// idx i = ((w*32 + fo)*64 + lane); fo = cb*8 + ks
// row = 768 + w*64 + cb*16 + (lane&15); k = ks*32 + (lane>>4)*8 + j
__global__ void k_packW8(const float* __restrict__ Whh, u64* __restrict__ pk) {
  int i = blockIdx.x * blockDim.x + threadIdx.x;   // 8192
  int lane = i & 63;
  int fo = (i >> 6) & 31;
  int w  = i >> 11;
  int cb = fo >> 3, ks = fo & 7;
  int row = 768 + w * 64 + cb * 16 + (lane & 15);
  int kb  = ks * 32 + (lane >> 4) * 8;
  const float* src = Whh + (size_t)row * 256 + kb;
  u64 p = 0;
  #pragma unroll
  for (int j = 0; j < 8; j++)
    p |= ((u64)f32_to_e4m3(src[j])) << (8 * j);
  pk[i] = p;
}

// gamma = z@Wg.T + bg ; beta = z@Wb.T + bb   (each (16,256))
__global__ void k_film(const float* __restrict__ z,
                       const float* __restrict__ Wg, const float* __restrict__ bg,
                       const float* __restrict__ Wb, const float* __restrict__ bb,
                       float* __restrict__ gamma, float* __restrict__ beta) {
  int tid = blockIdx.x * blockDim.x + threadIdx.x;   // 8192
  int which = tid >> 12;
  int o = tid & 4095;
  int b = o >> 8, h = o & 255;
  const float* W  = which ? Wb : Wg;
  const float* bi = which ? bb : bg;
  float acc = bi[h];
  const float* zr = z + b * 256;
  const float* wr = W + h * 256;
  #pragma unroll 8
  for (int k = 0; k < 256; k++) acc += zr[k] * wr[k];
  (which ? beta : gamma)[o] = acc;
}

// x[b][t][:] = (seq[b][t]==0 ? 0 : emb[seq[b][t]])  as bf16
__global__ void k_gather(const int* __restrict__ seq, const float* __restrict__ emb,
                         u16* __restrict__ xb) {
  int i = blockIdx.x * blockDim.x + threadIdx.x;     // B*T*(E/4) = 262144
  int n = B_ * T_ * (H_ / 4);
  if (i >= n) return;
  int e4 = i & 63;
  int bt = i >> 6;
  int t = bt & 255, b = bt >> 8;
  int row = seq[b * 257 + t];
  short4v p;
  if (row == 0) {
    p[0] = 0; p[1] = 0; p[2] = 0; p[3] = 0;
  } else {
    const f32x4 v = *(const f32x4*)(emb + (size_t)row * 256 + e4 * 4);
    p[0] = (short)f2bf(v[0]); p[1] = (short)f2bf(v[1]);
    p[2] = (short)f2bf(v[2]); p[3] = (short)f2bf(v[3]);
  }
  *(short4v*)(xb + (size_t)bt * 256 + e4 * 4) = p;
}

// ------------------------------ bf16 GEMM ----------------------------------
// C(M,N) fp32 = A(M,K)bf16 @ B(N,K)bf16^T + bias(N). M,N mult of 128, K mult of 32.
// permX (N must be 1024): col = g*256 + r  ->  ocol = (r>>6)*256 + (r&63)*4 + g
// so the LSTM lane (w, lane) reads its 4 gate values as one f32x4.

__global__ __launch_bounds__(256) void k_gemm_bt(
    const u16* __restrict__ A, const u16* __restrict__ Bm,
    const float* __restrict__ bias, float* __restrict__ C,
    int M, int N, int K, int permX) {
  __shared__ u16 sA[128 * 40];
  __shared__ u16 sB[128 * 40];
  const int tid  = threadIdx.x;
  const int lane = tid & 63;
  const int wv   = tid >> 6;
  const int wr   = wv >> 1, wc = wv & 1;
  const int m0 = blockIdx.y * 128, n0 = blockIdx.x * 128;
  const int rr = tid >> 2;
  const int cc = (tid & 3) * 8;

  f32x4 acc[4][4];
  #pragma unroll
  for (int m = 0; m < 4; m++)
    #pragma unroll
    for (int n = 0; n < 4; n++) acc[m][n] = (f32x4){0.f, 0.f, 0.f, 0.f};

  for (int ks = 0; ks < K; ks += 32) {
    short8 va0 = *(const short8*)(A  + (size_t)(m0 + rr)      * K + ks + cc);
    short8 va1 = *(const short8*)(A  + (size_t)(m0 + rr + 64) * K + ks + cc);
    short8 vb0 = *(const short8*)(Bm + (size_t)(n0 + rr)      * K + ks + cc);
    short8 vb1 = *(const short8*)(Bm + (size_t)(n0 + rr + 64) * K + ks + cc);
    __syncthreads();
    *(short8*)&sA[(rr)      * 40 + cc] = va0;
    *(short8*)&sA[(rr + 64) * 40 + cc] = va1;
    *(short8*)&sB[(rr)      * 40 + cc] = vb0;
    *(short8*)&sB[(rr + 64) * 40 + cc] = vb1;
    __syncthreads();
    const int kc = (lane >> 4) * 8;
    short8 af[4], bfr[4];
    #pragma unroll
    for (int m = 0; m < 4; m++)
      af[m] = *(const short8*)&sA[(wr * 64 + m * 16 + (lane & 15)) * 40 + kc];
    #pragma unroll
    for (int n = 0; n < 4; n++)
      bfr[n] = *(const short8*)&sB[(wc * 64 + n * 16 + (lane & 15)) * 40 + kc];
    #pragma unroll
    for (int m = 0; m < 4; m++)
      #pragma unroll
      for (int n = 0; n < 4; n++)
        acc[m][n] = __builtin_amdgcn_mfma_f32_16x16x32_bf16(af[m], bfr[n], acc[m][n], 0, 0, 0);
  }

  #pragma unroll
  for (int m = 0; m < 4; m++) {
    int row = m0 + wr * 64 + m * 16 + ((lane >> 4) << 2);
    #pragma unroll
    for (int n = 0; n < 4; n++) {
      int col = n0 + wc * 64 + n * 16 + (lane & 15);
      float bv = bias[col];
      int ocol = col;
      if (permX) {
        int g = col >> 8, r = col & 255;
        ocol = (r >> 6) * 256 + (r & 63) * 4 + g;
      }
      #pragma unroll
      for (int i = 0; i < 4; i++)
        C[(size_t)(row + i) * N + ocol] = acc[m][n][i] + bv;
    }
  }
}

// ------------------------- per-sample LSTM ---------------------------------
// Block = one sample, 4 waves x 64 lanes, 1 wave/SIMD -> 512 regs/wave.
// Wave w owns hcols [w*64, w*64+64); lane l owns hcol hc = w*64 + l.
// Tiles: (gate, cb), cb = hcol block of 16. Lane's tile col = l&15, cb_l = l>>4.
// B-frags: bf16 wb[96] (gates i,f,g), fp8 w8[32] (gate o). A = h(t-1)
// replicated over 16 MFMA rows (bf16 from hbuf / e4m3 from h8buf).
// Phase A: gates i,f (acc 32); Phase B: g (bf16) + o (fp8) (acc 32).

__global__ __launch_bounds__(LTPB, 1) void k_lstm_sample(
    const float* __restrict__ Xpre,    // (B*T, 1024) fp32, permuted
    const u16* __restrict__ WpkB,      // packed bf16 frags (k_packWb)
    const u64* __restrict__ Wpk8,      // packed fp8 frags (k_packW8)
    u16* __restrict__ outb,            // (B,T,H) bf16
    const float* __restrict__ gamma, const float* __restrict__ beta,
    int mode) {
  __shared__ u16 hbuf[2][256];
  __shared__ u64 h8buf[2][32];         // 256 bytes of e4m3 h per buffer

  const int s    = blockIdx.x;
  const int tid  = threadIdx.x;
  const int lane = tid & 63;
  const int w    = tid >> 6;
  const int cb_l = (lane >> 4);        // lane's col-block AND its A-frag k-chunk
  const int hc   = w * 64 + lane;

  // ---- load all W frags into registers (coalesced; once) ----
  short8 wb[96];
  {
    const u16* bp = WpkB + ((size_t)(w * 96) * 64 + lane) * 8;
    #pragma unroll
    for (int f = 0; f < 96; ++f)
      wb[f] = *(const short8*)(bp + (size_t)f * 64 * 8);
  }
  u64 w8[32];
  {
    const u64* p8 = Wpk8 + (size_t)(w * 32) * 64 + lane;
    #pragma unroll
    for (int f = 0; f < 32; ++f)
      w8[f] = p8[(size_t)f * 64];
  }

  float cs = 0.f;
  float gm = 1.f, bt = 0.f;
  if (mode) { gm = gamma[s * 256 + hc]; bt = beta[s * 256 + hc]; }

  const float* xptr = Xpre + (size_t)s * T_ * 1024 + (size_t)(w * 256 + lane * 4);

  // ---- t = 0 (no recurrent term) ----
  {
    f32x4 xv = *(const f32x4*)xptr;
    float cn = sigf(xv[1]) * cs + sigf(xv[0]) * tanhfast(xv[2]);
    float hn = sigf(xv[3]) * tanhfast(cn);
    cs = cn;
    u16 hv = f2bf(hn);
    hbuf[0][hc] = hv;
    ((uint8_t*)h8buf[0])[hc] = (uint8_t)f32_to_e4m3(hn);
    outb[(size_t)(s * T_) * 256 + hc] = mode ? f2bf(gm * hn + bt) : hv;
  }
  asm volatile("s_waitcnt lgkmcnt(0)" ::: "memory");
  __builtin_amdgcn_sched_barrier(0);
  __builtin_amdgcn_s_barrier();
  __builtin_amdgcn_sched_barrier(0);

  f32x4 xn = *(const f32x4*)(xptr + 1024);   // X for t=1

  for (int t = 1; t < T_; ++t) {
    // prefetch X for t+1 (clamped)
    f32x4 xf = *(const f32x4*)(xptr + (size_t)((t + 1 < T_) ? t + 1 : t) * 1024);

    const u16* hrd = hbuf[(t + 1) & 1];
    const u64* h8rd = h8buf[(t + 1) & 1];

    // ---- Phase A: gates i (acc 0-3), f (acc 4-7), bf16 ----
    f32x4 accA[8];
    #pragma unroll
    for (int i = 0; i < 8; ++i) accA[i] = (f32x4){0.f, 0.f, 0.f, 0.f};
    #pragma unroll
    for (int ks = 0; ks < 8; ++ks) {
      short8 a = *(const short8*)&hrd[ks * 32 + cb_l * 8];
      #pragma unroll
      for (int cb = 0; cb < 4; ++cb) {
        accA[cb]     = __builtin_amdgcn_mfma_f32_16x16x32_bf16(a, wb[cb * 8 + ks],        accA[cb],     0, 0, 0);
        accA[4 + cb] = __builtin_amdgcn_mfma_f32_16x16x32_bf16(a, wb[32 + cb * 8 + ks],   accA[4 + cb], 0, 0, 0);
      }
    }
    float iv = sel4(cb_l, accA[0][0], accA[1][0], accA[2][0], accA[3][0]) + xn[0];
    float fv = sel4(cb_l, accA[4][0], accA[5][0], accA[6][0], accA[7][0]) + xn[1];

    // ---- Phase B: gate g (bf16, acc 0-3) + gate o (fp8, acc 4-7) ----
    f32x4 accB[8];
    #pragma unroll
    for (int i = 0; i < 8; ++i) accB[i] = (f32x4){0.f, 0.f, 0.f, 0.f};
    #pragma unroll
    for (int ks = 0; ks < 8; ++ks) {
      short8 a = *(const short8*)&hrd[ks * 32 + cb_l * 8];
      u64 a8 = h8rd[ks * 4 + cb_l];
      #pragma unroll
      for (int cb = 0; cb < 4; ++cb) {
        accB[cb]     = __builtin_amdgcn_mfma_f32_16x16x32_bf16(a, wb[64 + cb * 8 + ks], accB[cb], 0, 0, 0);
        accB[4 + cb] = __builtin_amdgcn_mfma_f32_16x16x32_fp8_fp8(
            (long)a8, (long)w8[cb * 8 + ks], accB[4 + cb], 0, 0, 0);
      }
    }
    float gv = sel4(cb_l, accB[0][0], accB[1][0], accB[2][0], accB[3][0]) + xn[2];
    float ov = sel4(cb_l, accB[4][0], accB[5][0], accB[6][0], accB[7][0]) + xn[3];

    // ---- nonlinearity + h writeback ----
    float cn = sigf(fv) * cs + sigf(iv) * tanhfast(gv);
    float hn = sigf(ov) * tanhfast(cn);
    cs = cn;
    u16 hv = f2bf(hn);
    hbuf[t & 1][hc] = hv;
    ((uint8_t*)h8buf[t & 1])[hc] = (uint8_t)f32_to_e4m3(hn);
    outb[((size_t)(s * T_ + t)) * 256 + hc] = mode ? f2bf(gm * hn + bt) : hv;

    asm volatile("s_waitcnt lgkmcnt(0)" ::: "memory");
    __builtin_amdgcn_sched_barrier(0);
    __builtin_amdgcn_s_barrier();
    __builtin_amdgcn_sched_barrier(0);

    xn = xf;
  }
}

// ------------------------------ launcher -----------------------------------

extern "C" void kernel_launch(void* const* d_in, const int* in_sizes, int n_in,
                              void* d_out, int out_size, void* d_ws, size_t ws_size,
                              hipStream_t stream) {
  const float* z    = (const float*)d_in[0];
  const int*   seq  = (const int*)  d_in[1];
  const float* emb  = (const float*)d_in[2];
  const float* Wg   = (const float*)d_in[3];
  const float* bg   = (const float*)d_in[4];
  const float* Wb   = (const float*)d_in[5];
  const float* bb   = (const float*)d_in[6];
  const float* Wih0 = (const float*)d_in[7];
  const float* Whh0 = (const float*)d_in[8];
  const float* bih0 = (const float*)d_in[9];
  const float* bhh0 = (const float*)d_in[10];
  const float* Wih1 = (const float*)d_in[11];
  const float* Whh1 = (const float*)d_in[12];
  const float* bih1 = (const float*)d_in[13];
  const float* bhh1 = (const float*)d_in[14];
  const float* Wout = (const float*)d_in[15];
  const float* bout = (const float*)d_in[16];

  char* ws = (char*)d_ws;
  size_t off = 0;
  auto take = [&](size_t bytes) -> char* {
    char* p = ws + off;
    off = (off + bytes + 255) & ~(size_t)255;
    return p;
  };
  float* gamma  = (float*)take(B_ * H_ * 4);
  float* beta   = (float*)take(B_ * H_ * 4);
  float* b01    = (float*)take(G4 * 4);
  float* b11    = (float*)take(G4 * 4);
  u16*   Wih0b  = (u16*)  take((size_t)G4 * H_ * 2);
  u16*   Wih1b  = (u16*)  take((size_t)G4 * H_ * 2);
  u16*   WpB0   = (u16*)  take((size_t)4 * 96 * 64 * 8 * 2);   // 384 KB
  u64*   Wp80   = (u64*)  take((size_t)4 * 32 * 64 * 8);       // 64 KB
  u16*   WpB1   = (u16*)  take((size_t)4 * 96 * 64 * 8 * 2);
  u64*   Wp81   = (u64*)  take((size_t)4 * 32 * 64 * 8);
  u16*   Woutb  = (u16*)  take((size_t)V_ * H_ * 2);
  u16*   xb     = (u16*)  take((size_t)B_ * T_ * H_ * 2);
  float* X      = (float*)take((size_t)B_ * T_ * G4 * 4);
  u16*   h1b    = (u16*)  take((size_t)B_ * T_ * H_ * 2);
  u16*   filmb  = (u16*)  take((size_t)B_ * T_ * H_ * 2);
  (void)ws_size; (void)in_sizes; (void)n_in; (void)out_size;

  // prep
  k_convert<<<256, 256, 0, stream>>>(Wih0, Wih0b, G4 * H_);
  k_convert<<<256, 256, 0, stream>>>(Wih1, Wih1b, G4 * H_);
  k_convert<<<1024, 256, 0, stream>>>(Wout, Woutb, V_ * H_);
  k_packWb<<<96, 256, 0, stream>>>(Whh0, WpB0);
  k_packW8<<<32, 256, 0, stream>>>(Whh0, Wp80);
  k_packWb<<<96, 256, 0, stream>>>(Whh1, WpB1);
  k_packW8<<<32, 256, 0, stream>>>(Whh1, Wp81);
  k_addbias<<<4, 256, 0, stream>>>(bih0, bhh0, b01, G4);
  k_addbias<<<4, 256, 0, stream>>>(bih1, bhh1, b11, G4);
  k_film<<<32, 256, 0, stream>>>(z, Wg, bg, Wb, bb, gamma, beta);
  k_gather<<<1024, 256, 0, stream>>>(seq, emb, xb);

  // layer 0 input projection (permuted X layout)
  k_gemm_bt<<<dim3(G4 / 128, (B_ * T_) / 128), 256, 0, stream>>>(
      xb, Wih0b, b01, X, B_ * T_, G4, H_, 1);

  // layer 0 recurrence: one block per sample
  k_lstm_sample<<<B_, LTPB, 0, stream>>>(X, WpB0, Wp80, h1b, gamma, beta, 0);

  // layer 1 input projection (permuted X layout)
  k_gemm_bt<<<dim3(G4 / 128, (B_ * T_) / 128), 256, 0, stream>>>(
      h1b, Wih1b, b11, X, B_ * T_, G4, H_, 1);

  // layer 1 recurrence (FiLM fused into output)
  k_lstm_sample<<<B_, LTPB, 0, stream>>>(X, WpB1, Wp81, filmb, gamma, beta, 1);

  // logits = filmed @ Wout^T + b_out
  k_gemm_bt<<<dim3(V_ / 128, (B_ * T_) / 128), 256, 0, stream>>>(
      filmb, Woutb, bout, (float*)d_out, B_ * T_, V_, H_, 0);
}

// Round 9
// 1154.490 us; speedup vs baseline: 2.1948x; 1.4702x over previous
//
#include <hip/hip_runtime.h>
#include <stdint.h>

// ---------------------------------------------------------------------------
// ConditionalDecoder: emb-gather -> LSTM x2 -> FiLM -> vocab GEMM
// B=16, T=256, V=32000, E=H=Z=256, 4H=1024
// Round 9: r5 wave structure (8 waves, 2/SIMD) + FULL W registration via
//   mixed precision, builtins only (no inline-asm MFMA -- r8's NaN was
//   missing hazard nops around asm):
//   - g gate bf16: 16 frags = 64 VGPR
//   - i,f,o gates fp8 e4m3: 48 frags = 96 VGPR (encoder proven in r7)
//   - total ~230 regs <= 256-per-wave cap at 2 waves/SIMD -> no spills
//   - LDS only h double-buffer (bf16 + e4m3 mirrors), raw s_barrier/step
// ---------------------------------------------------------------------------

#define B_  16
#define T_  256
#define H_  256
#define V_  32000
#define G4  1024

#define LTPB 512   // 8 waves

typedef unsigned short u16;
typedef unsigned long long u64;
typedef __attribute__((ext_vector_type(8))) short  short8;
typedef __attribute__((ext_vector_type(4))) short  short4v;
typedef __attribute__((ext_vector_type(4))) float  f32x4;

static __device__ __forceinline__ float bf2f(u16 u) {
  uint32_t i = ((uint32_t)u) << 16;
  return __builtin_bit_cast(float, i);
}
static __device__ __forceinline__ u16 f2bf(float f) {
  uint32_t i = __builtin_bit_cast(uint32_t, f);
  uint32_t lsb = (i >> 16) & 1u;
  i += 0x7fffu + lsb;
  return (u16)(i >> 16);
}
static __device__ __forceinline__ float sigf(float x) {
  return 1.0f / (1.0f + __expf(-x));
}
static __device__ __forceinline__ float tanhfast(float x) {
  return 1.0f - 2.0f / (1.0f + __expf(2.0f * x));
}

// OCP e4m3fn encode (bias 7, max finite 448 = 0x7E, RNE). Used for BOTH the
// packed W bytes and the per-step h bytes -> A/B formats match by construction.
static __device__ __forceinline__ uint32_t f32_to_e4m3(float f) {
  uint32_t u = __builtin_bit_cast(uint32_t, f);
  uint32_t s = (u >> 24) & 0x80u;
  uint32_t mag = u & 0x7fffffffu;
  if (mag >= 0x43E00000u) return s | 0x7Eu;          // >=448 -> 448
  if (mag < 0x3C800000u) {                           // < 2^-6 -> subnormal
    float af = __builtin_bit_cast(float, mag);
    int q = (int)rintf(af * 512.0f);                 // value = q * 2^-9
    if (q >= 8) return s | 0x08u;
    return s | (uint32_t)q;
  }
  uint32_t lsb = (mag >> 20) & 1u;
  mag += 0x7ffffu + lsb;                             // RNE on 20 dropped bits
  int e = (int)(mag >> 23) - 120;                    // -127 + 7
  uint32_t m3 = (mag >> 20) & 7u;
  if (e >= 16) return s | 0x7Eu;
  return s | ((uint32_t)e << 3) | m3;
}

// ------------------------------ prep kernels -------------------------------

__global__ void k_convert(const float* __restrict__ src, u16* __restrict__ dst, int n) {
  int i = blockIdx.x * blockDim.x + threadIdx.x;
  int stride = gridDim.x * blockDim.x;
  for (; i < n; i += stride) dst[i] = f2bf(src[i]);
}

__global__ void k_addbias(const float* __restrict__ a, const float* __restrict__ b,
                          float* __restrict__ dst, int n) {
  int i = blockIdx.x * blockDim.x + threadIdx.x;
  if (i < n) dst[i] = a[i] + b[i];
}

// Pack bf16 W frags for the g (candidate) gate: 16 frags/wave (8 waves).
// idx = ((w*16 + cb*8 + ks)*64 + lane); row = 512 + w*32 + cb*16 + (lane&15);
// k = ks*32 + (lane>>4)*8 + j
__global__ void k_packWg(const float* __restrict__ Whh, u16* __restrict__ pk) {
  int i = blockIdx.x * blockDim.x + threadIdx.x;   // 8192
  int lane = i & 63;
  int fb = (i >> 6) & 15;
  int w  = i >> 10;
  int cb = fb >> 3, ks = fb & 7;
  int row = 512 + w * 32 + cb * 16 + (lane & 15);
  int kb  = ks * 32 + (lane >> 4) * 8;
  const float* src = Whh + (size_t)row * 256 + kb;
  short8 v;
  #pragma unroll
  for (int j = 0; j < 8; j++) v[j] = (short)f2bf(src[j]);
  *(short8*)(pk + (size_t)i * 8) = v;
}

// Pack fp8 W frags for gates i,f,o: 48 frags/wave (8 waves).
// idx = ((w*48 + g8*16 + cb*8 + ks)*64 + lane); gate row base {0,256,768};
// row = base + w*32 + cb*16 + (lane&15); k = ks*32 + (lane>>4)*8 + j
__global__ void k_packW8(const float* __restrict__ Whh, u64* __restrict__ pk) {
  int i = blockIdx.x * blockDim.x + threadIdx.x;   // 24576
  int lane = i & 63;
  int fo = (i >> 6) % 48;
  int w  = (i >> 6) / 48;
  int g8 = fo >> 4, cb = (fo >> 3) & 1, ks = fo & 7;
  int base = (g8 == 0) ? 0 : (g8 == 1 ? 256 : 768);
  int row = base + w * 32 + cb * 16 + (lane & 15);
  int kb  = ks * 32 + (lane >> 4) * 8;
  const float* src = Whh + (size_t)row * 256 + kb;
  u64 p = 0;
  #pragma unroll
  for (int j = 0; j < 8; j++)
    p |= ((u64)f32_to_e4m3(src[j])) << (8 * j);
  pk[i] = p;
}

// gamma = z@Wg.T + bg ; beta = z@Wb.T + bb   (each (16,256))
__global__ void k_film(const float* __restrict__ z,
                       const float* __restrict__ Wg, const float* __restrict__ bg,
                       const float* __restrict__ Wb, const float* __restrict__ bb,
                       float* __restrict__ gamma, float* __restrict__ beta) {
  int tid = blockIdx.x * blockDim.x + threadIdx.x;   // 8192
  int which = tid >> 12;
  int o = tid & 4095;
  int b = o >> 8, h = o & 255;
  const float* W  = which ? Wb : Wg;
  const float* bi = which ? bb : bg;
  float acc = bi[h];
  const float* zr = z + b * 256;
  const float* wr = W + h * 256;
  #pragma unroll 8
  for (int k = 0; k < 256; k++) acc += zr[k] * wr[k];
  (which ? beta : gamma)[o] = acc;
}

// x[b][t][:] = (seq[b][t]==0 ? 0 : emb[seq[b][t]])  as bf16
__global__ void k_gather(const int* __restrict__ seq, const float* __restrict__ emb,
                         u16* __restrict__ xb) {
  int i = blockIdx.x * blockDim.x + threadIdx.x;     // B*T*(E/4) = 262144
  int n = B_ * T_ * (H_ / 4);
  if (i >= n) return;
  int e4 = i & 63;
  int bt = i >> 6;
  int t = bt & 255, b = bt >> 8;
  int row = seq[b * 257 + t];
  short4v p;
  if (row == 0) {
    p[0] = 0; p[1] = 0; p[2] = 0; p[3] = 0;
  } else {
    const f32x4 v = *(const f32x4*)(emb + (size_t)row * 256 + e4 * 4);
    p[0] = (short)f2bf(v[0]); p[1] = (short)f2bf(v[1]);
    p[2] = (short)f2bf(v[2]); p[3] = (short)f2bf(v[3]);
  }
  *(short4v*)(xb + (size_t)bt * 256 + e4 * 4) = p;
}

// ------------------------------ bf16 GEMM ----------------------------------
// C(M,N) fp32 = A(M,K)bf16 @ B(N,K)bf16^T + bias(N). M,N mult of 128, K mult of 32.
// permX (N must be 1024): col = g*256 + r; ocol = (r>>5)*128 + (r&15)*8
//   + g*2 + ((r>>4)&1)  -> LSTM lane (w,l15) reads its 8 gate values as 2 f32x4
//   at X + bt*1024 + (w*16+l15)*8, order {i0,i1,f0,f1,g0,g1,o0,o1}.

__global__ __launch_bounds__(256) void k_gemm_bt(
    const u16* __restrict__ A, const u16* __restrict__ Bm,
    const float* __restrict__ bias, float* __restrict__ C,
    int M, int N, int K, int permX) {
  __shared__ u16 sA[128 * 40];
  __shared__ u16 sB[128 * 40];
  const int tid  = threadIdx.x;
  const int lane = tid & 63;
  const int wv   = tid >> 6;
  const int wr   = wv >> 1, wc = wv & 1;
  const int m0 = blockIdx.y * 128, n0 = blockIdx.x * 128;
  const int rr = tid >> 2;
  const int cc = (tid & 3) * 8;

  f32x4 acc[4][4];
  #pragma unroll
  for (int m = 0; m < 4; m++)
    #pragma unroll
    for (int n = 0; n < 4; n++) acc[m][n] = (f32x4){0.f, 0.f, 0.f, 0.f};

  for (int ks = 0; ks < K; ks += 32) {
    short8 va0 = *(const short8*)(A  + (size_t)(m0 + rr)      * K + ks + cc);
    short8 va1 = *(const short8*)(A  + (size_t)(m0 + rr + 64) * K + ks + cc);
    short8 vb0 = *(const short8*)(Bm + (size_t)(n0 + rr)      * K + ks + cc);
    short8 vb1 = *(const short8*)(Bm + (size_t)(n0 + rr + 64) * K + ks + cc);
    __syncthreads();
    *(short8*)&sA[(rr)      * 40 + cc] = va0;
    *(short8*)&sA[(rr + 64) * 40 + cc] = va1;
    *(short8*)&sB[(rr)      * 40 + cc] = vb0;
    *(short8*)&sB[(rr + 64) * 40 + cc] = vb1;
    __syncthreads();
    const int kc = (lane >> 4) * 8;
    short8 af[4], bfr[4];
    #pragma unroll
    for (int m = 0; m < 4; m++)
      af[m] = *(const short8*)&sA[(wr * 64 + m * 16 + (lane & 15)) * 40 + kc];
    #pragma unroll
    for (int n = 0; n < 4; n++)
      bfr[n] = *(const short8*)&sB[(wc * 64 + n * 16 + (lane & 15)) * 40 + kc];
    #pragma unroll
    for (int m = 0; m < 4; m++)
      #pragma unroll
      for (int n = 0; n < 4; n++)
        acc[m][n] = __builtin_amdgcn_mfma_f32_16x16x32_bf16(af[m], bfr[n], acc[m][n], 0, 0, 0);
  }

  #pragma unroll
  for (int m = 0; m < 4; m++) {
    int row = m0 + wr * 64 + m * 16 + ((lane >> 4) << 2);
    #pragma unroll
    for (int n = 0; n < 4; n++) {
      int col = n0 + wc * 64 + n * 16 + (lane & 15);
      float bv = bias[col];
      int ocol = col;
      if (permX) {
        int g = col >> 8, r = col & 255;
        ocol = (r >> 5) * 128 + (r & 15) * 8 + g * 2 + ((r >> 4) & 1);
      }
      #pragma unroll
      for (int i = 0; i < 4; i++)
        C[(size_t)(row + i) * N + ocol] = acc[m][n][i] + bv;
    }
  }
}

// ------------------------- per-sample LSTM ---------------------------------
// Block = one sample, 8 waves x 64 lanes, 2 waves/SIMD (256 regs/wave cap).
// Wave w owns hcols [w*32, w*32+32): col-blocks cb in {0,1}; lane computes
// hcols col0 = w*32 + (lane&15) and col1 = col0+16 (acc row-replicated).
// W residency (ALL in VGPR, builtins only):
//   g gate bf16: wgm[16] (64 regs); i,f,o gates fp8 e4m3: w8r[48] (96 regs).
// A = h(t-1) replicated over 16 MFMA rows: bf16 from hbuf, e4m3 from h8buf.
// Raw s_barrier per step (LDS-only handoff; X prefetch stays in flight).

__global__ __launch_bounds__(LTPB, 2) void k_lstm_sample(
    const float* __restrict__ Xpre,    // (B*T, 1024) fp32, permuted
    const u16* __restrict__ WpkG,      // packed bf16 g-gate frags
    const u64* __restrict__ Wpk8,      // packed fp8 i,f,o frags
    u16* __restrict__ outb,            // (B,T,H) bf16
    const float* __restrict__ gamma, const float* __restrict__ beta,
    int mode) {
  __shared__ u16 hbuf[2][256];
  __shared__ u64 h8buf[2][32];         // 256 B of e4m3 h per buffer

  const int s    = blockIdx.x;
  const int tid  = threadIdx.x;
  const int lane = tid & 63;
  const int w    = tid >> 6;
  const int l15  = lane & 15;
  const int lhi  = lane >> 4;

  // ---- load all W frags into registers (coalesced; once) ----
  short8 wgm[16];
  {
    const u16* bp = WpkG + ((size_t)(w * 16) * 64 + lane) * 8;
    #pragma unroll
    for (int f = 0; f < 16; ++f)
      wgm[f] = *(const short8*)(bp + (size_t)f * 512);
  }
  u64 w8r[48];
  {
    const u64* p8 = Wpk8 + (size_t)(w * 48) * 64 + lane;
    #pragma unroll
    for (int f = 0; f < 48; ++f)
      w8r[f] = p8[(size_t)f * 64];
  }

  const int col0 = w * 32 + l15;
  const int col1 = col0 + 16;
  float cs0 = 0.f, cs1 = 0.f;
  float gm0 = 1.f, gm1 = 1.f, bt0 = 0.f, bt1 = 0.f;
  if (mode) {
    gm0 = gamma[s * 256 + col0]; bt0 = beta[s * 256 + col0];
    gm1 = gamma[s * 256 + col1]; bt1 = beta[s * 256 + col1];
  }

  const float* xptr = Xpre + (size_t)s * T_ * 1024 + (size_t)(w * 16 + l15) * 8;

  // ---- t = 0 (no recurrent term) ----
  f32x4 xa = *(const f32x4*)(xptr);
  f32x4 xg = *(const f32x4*)(xptr + 4);
  {
    float cn0 = sigf(xa[2]) * cs0 + sigf(xa[0]) * tanhfast(xg[0]);
    float hn0 = sigf(xg[2]) * tanhfast(cn0);
    cs0 = cn0;
    float cn1 = sigf(xa[3]) * cs1 + sigf(xa[1]) * tanhfast(xg[1]);
    float hn1 = sigf(xg[3]) * tanhfast(cn1);
    cs1 = cn1;
    u16 h0 = f2bf(hn0), h1 = f2bf(hn1);
    if (lhi == 0) {
      hbuf[0][col0] = h0;
      hbuf[0][col1] = h1;
      ((uint8_t*)h8buf[0])[col0] = (uint8_t)f32_to_e4m3(hn0);
      ((uint8_t*)h8buf[0])[col1] = (uint8_t)f32_to_e4m3(hn1);
      outb[(size_t)(s * T_) * 256 + col0] = mode ? f2bf(gm0 * hn0 + bt0) : h0;
      outb[(size_t)(s * T_) * 256 + col1] = mode ? f2bf(gm1 * hn1 + bt1) : h1;
    }
  }
  asm volatile("s_waitcnt lgkmcnt(0)" ::: "memory");
  __builtin_amdgcn_sched_barrier(0);
  __builtin_amdgcn_s_barrier();
  __builtin_amdgcn_sched_barrier(0);

  // preload X for t=1
  xa = *(const f32x4*)(xptr + 1024);
  xg = *(const f32x4*)(xptr + 1024 + 4);

  for (int t = 1; t < T_; ++t) {
    // prefetch X for t+1 (clamped) -- consumed next iteration
    const float* xn = xptr + (size_t)((t + 1 < T_) ? t + 1 : t) * 1024;
    f32x4 na = *(const f32x4*)(xn);
    f32x4 ng = *(const f32x4*)(xn + 4);

    const u16* hrd  = hbuf[(t + 1) & 1];
    const u64* h8rd = h8buf[(t + 1) & 1];

    // ---- MFMA: h(t-1) @ Whh^T, all B-frags register-resident ----
    f32x4 aI[2], aF[2], aG[2], aO[2];
    #pragma unroll
    for (int i = 0; i < 2; ++i) {
      aI[i] = (f32x4){0.f, 0.f, 0.f, 0.f};
      aF[i] = (f32x4){0.f, 0.f, 0.f, 0.f};
      aG[i] = (f32x4){0.f, 0.f, 0.f, 0.f};
      aO[i] = (f32x4){0.f, 0.f, 0.f, 0.f};
    }
    #pragma unroll
    for (int ks = 0; ks < 8; ++ks) {
      short8 a  = *(const short8*)&hrd[ks * 32 + lhi * 8];
      u64    a8 = h8rd[ks * 4 + lhi];
      aG[0] = __builtin_amdgcn_mfma_f32_16x16x32_bf16(a, wgm[ks],     aG[0], 0, 0, 0);
      aG[1] = __builtin_amdgcn_mfma_f32_16x16x32_bf16(a, wgm[8 + ks], aG[1], 0, 0, 0);
      aI[0] = __builtin_amdgcn_mfma_f32_16x16x32_fp8_fp8((long)a8, (long)w8r[ks],      aI[0], 0, 0, 0);
      aI[1] = __builtin_amdgcn_mfma_f32_16x16x32_fp8_fp8((long)a8, (long)w8r[8 + ks],  aI[1], 0, 0, 0);
      aF[0] = __builtin_amdgcn_mfma_f32_16x16x32_fp8_fp8((long)a8, (long)w8r[16 + ks], aF[0], 0, 0, 0);
      aF[1] = __builtin_amdgcn_mfma_f32_16x16x32_fp8_fp8((long)a8, (long)w8r[24 + ks], aF[1], 0, 0, 0);
      aO[0] = __builtin_amdgcn_mfma_f32_16x16x32_fp8_fp8((long)a8, (long)w8r[32 + ks], aO[0], 0, 0, 0);
      aO[1] = __builtin_amdgcn_mfma_f32_16x16x32_fp8_fp8((long)a8, (long)w8r[40 + ks], aO[1], 0, 0, 0);
    }

    // ---- nonlinearity (rows replicated; row-0 slice in acc[.][0]) ----
    float iv0 = aI[0][0] + xa[0], iv1 = aI[1][0] + xa[1];
    float fv0 = aF[0][0] + xa[2], fv1 = aF[1][0] + xa[3];
    float gv0 = aG[0][0] + xg[0], gv1 = aG[1][0] + xg[1];
    float ov0 = aO[0][0] + xg[2], ov1 = aO[1][0] + xg[3];

    float cn0 = sigf(fv0) * cs0 + sigf(iv0) * tanhfast(gv0);
    float hn0 = sigf(ov0) * tanhfast(cn0);
    cs0 = cn0;
    float cn1 = sigf(fv1) * cs1 + sigf(iv1) * tanhfast(gv1);
    float hn1 = sigf(ov1) * tanhfast(cn1);
    cs1 = cn1;

    u16 h0 = f2bf(hn0), h1 = f2bf(hn1);
    if (lhi == 0) {
      hbuf[t & 1][col0] = h0;
      hbuf[t & 1][col1] = h1;
      ((uint8_t*)h8buf[t & 1])[col0] = (uint8_t)f32_to_e4m3(hn0);
      ((uint8_t*)h8buf[t & 1])[col1] = (uint8_t)f32_to_e4m3(hn1);
      outb[((size_t)(s * T_ + t)) * 256 + col0] = mode ? f2bf(gm0 * hn0 + bt0) : h0;
      outb[((size_t)(s * T_ + t)) * 256 + col1] = mode ? f2bf(gm1 * hn1 + bt1) : h1;
    }

    // ---- raw barrier: LDS drained, VMEM left in flight ----
    asm volatile("s_waitcnt lgkmcnt(0)" ::: "memory");
    __builtin_amdgcn_sched_barrier(0);
    __builtin_amdgcn_s_barrier();
    __builtin_amdgcn_sched_barrier(0);

    xa = na;
    xg = ng;
  }
}

// ------------------------------ launcher -----------------------------------

extern "C" void kernel_launch(void* const* d_in, const int* in_sizes, int n_in,
                              void* d_out, int out_size, void* d_ws, size_t ws_size,
                              hipStream_t stream) {
  const float* z    = (const float*)d_in[0];
  const int*   seq  = (const int*)  d_in[1];
  const float* emb  = (const float*)d_in[2];
  const float* Wg   = (const float*)d_in[3];
  const float* bg   = (const float*)d_in[4];
  const float* Wb   = (const float*)d_in[5];
  const float* bb   = (const float*)d_in[6];
  const float* Wih0 = (const float*)d_in[7];
  const float* Whh0 = (const float*)d_in[8];
  const float* bih0 = (const float*)d_in[9];
  const float* bhh0 = (const float*)d_in[10];
  const float* Wih1 = (const float*)d_in[11];
  const float* Whh1 = (const float*)d_in[12];
  const float* bih1 = (const float*)d_in[13];
  const float* bhh1 = (const float*)d_in[14];
  const float* Wout = (const float*)d_in[15];
  const float* bout = (const float*)d_in[16];

  char* ws = (char*)d_ws;
  size_t off = 0;
  auto take = [&](size_t bytes) -> char* {
    char* p = ws + off;
    off = (off + bytes + 255) & ~(size_t)255;
    return p;
  };
  float* gamma  = (float*)take(B_ * H_ * 4);
  float* beta   = (float*)take(B_ * H_ * 4);
  float* b01    = (float*)take(G4 * 4);
  float* b11    = (float*)take(G4 * 4);
  u16*   Wih0b  = (u16*)  take((size_t)G4 * H_ * 2);
  u16*   Wih1b  = (u16*)  take((size_t)G4 * H_ * 2);
  u16*   WpG0   = (u16*)  take((size_t)8 * 16 * 64 * 8 * 2);   // 128 KB
  u64*   Wp80   = (u64*)  take((size_t)8 * 48 * 64 * 8);       // 192 KB
  u16*   WpG1   = (u16*)  take((size_t)8 * 16 * 64 * 8 * 2);
  u64*   Wp81   = (u64*)  take((size_t)8 * 48 * 64 * 8);
  u16*   Woutb  = (u16*)  take((size_t)V_ * H_ * 2);
  u16*   xb     = (u16*)  take((size_t)B_ * T_ * H_ * 2);
  float* X      = (float*)take((size_t)B_ * T_ * G4 * 4);
  u16*   h1b    = (u16*)  take((size_t)B_ * T_ * H_ * 2);
  u16*   filmb  = (u16*)  take((size_t)B_ * T_ * H_ * 2);
  (void)ws_size; (void)in_sizes; (void)n_in; (void)out_size;

  // prep
  k_convert<<<256, 256, 0, stream>>>(Wih0, Wih0b, G4 * H_);
  k_convert<<<256, 256, 0, stream>>>(Wih1, Wih1b, G4 * H_);
  k_convert<<<1024, 256, 0, stream>>>(Wout, Woutb, V_ * H_);
  k_packWg<<<32, 256, 0, stream>>>(Whh0, WpG0);
  k_packW8<<<96, 256, 0, stream>>>(Whh0, Wp80);
  k_packWg<<<32, 256, 0, stream>>>(Whh1, WpG1);
  k_packW8<<<96, 256, 0, stream>>>(Whh1, Wp81);
  k_addbias<<<4, 256, 0, stream>>>(bih0, bhh0, b01, G4);
  k_addbias<<<4, 256, 0, stream>>>(bih1, bhh1, b11, G4);
  k_film<<<32, 256, 0, stream>>>(z, Wg, bg, Wb, bb, gamma, beta);
  k_gather<<<1024, 256, 0, stream>>>(seq, emb, xb);

  // layer 0 input projection (permuted X layout)
  k_gemm_bt<<<dim3(G4 / 128, (B_ * T_) / 128), 256, 0, stream>>>(
      xb, Wih0b, b01, X, B_ * T_, G4, H_, 1);

  // layer 0 recurrence: one block per sample
  k_lstm_sample<<<B_, LTPB, 0, stream>>>(X, WpG0, Wp80, h1b, gamma, beta, 0);

  // layer 1 input projection (permuted X layout)
  k_gemm_bt<<<dim3(G4 / 128, (B_ * T_) / 128), 256, 0, stream>>>(
      h1b, Wih1b, b11, X, B_ * T_, G4, H_, 1);

  // layer 1 recurrence (FiLM fused into output)
  k_lstm_sample<<<B_, LTPB, 0, stream>>>(X, WpG1, Wp81, filmb, gamma, beta, 1);

  // logits = filmed @ Wout^T + b_out
  k_gemm_bt<<<dim3(V_ / 128, (B_ * T_) / 128), 256, 0, stream>>>(
      filmb, Woutb, bout, (float*)d_out, B_ * T_, V_, H_, 0);
}